// Round 2
// baseline (1011.141 us; speedup 1.0000x reference)
//
#include <hip/hip_runtime.h>

#define HH 384
#define WW 384
#define HWSZ (HH * WW)
#define NIMG 24

// packed coefficient table offsets (floats)
#define SYM0 0
#define ASYM0 126
#define SYM1 238
#define ASYM1 490
#define SYM2 714
#define ASYM2 1218

__device__ __forceinline__ int refl(int i, int n) {
    if (i < 0) i = -i;
    if (i >= n) i = 2 * n - 2 - i;
    return i;
}

// 5-tap Gaussian (sigma=1, normalized), double-precision constants cast to float
__device__ const float LPW[5] = {
    0.054488684549642945f, 0.24420134200323332f, 0.40261994689424746f,
    0.24420134200323332f, 0.054488684549642945f
};

// ---------------- filter generation (on device, fp64, matches numpy) -------
// Writes NORMALIZED fp64 filters to gtmp[28][225].
__global__ __launch_bounds__(256) void gen_filters(double* __restrict__ gtmp) {
    int f = blockIdx.x;  // 0..27
    int s, d, nd;
    if (f < 4)       { s = 0; nd = 4;  d = f;      }
    else if (f < 12) { s = 1; nd = 8;  d = f - 4;  }
    else             { s = 2; nd = 16; d = f - 12; }

    double angle = M_PI * (double)d / (double)nd;
    double scale = (double)(s + 1);
    double sx = 2.0 * scale, sy = 0.5 * scale;

    int tid = threadIdx.x;
    double val = 0.0;
    if (tid < 225) {
        int row = tid / 15, col = tid % 15;
        double X = (double)(col - 7);
        double Y = (double)(row - 7);
        double ca = cos(angle), sa = sin(angle);
        double Xr = X * ca - Y * sa;
        double Yr = X * sa + Y * ca;
        val = exp(-0.5 * (Xr * Xr / (sx * sx) + Yr * Yr / (sy * sy))) * Xr / (sx * sx);
    }

    __shared__ double red[256];
    red[tid] = val;
    __syncthreads();
    for (int st = 128; st > 0; st >>= 1) {
        if (tid < st) red[tid] += red[tid + st];
        __syncthreads();
    }
    double mean = red[0] / 225.0;
    __syncthreads();

    double dv = (tid < 225) ? (val - mean) : 0.0;
    red[tid] = dv * dv;
    __syncthreads();
    for (int st = 128; st > 0; st >>= 1) {
        if (tid < st) red[tid] += red[tid + st];
        __syncthreads();
    }
    double nrm = sqrt(red[0]);
    double inv = (nrm > 1e-6) ? (1.0 / nrm) : 1.0;

    if (tid < 225) {
        gtmp[(long)f * 225 + tid] = (val - mean) * inv;
    }
}

// ---------------- pack mirror-pair coefficient tables (fp64 combine) -------
// Exploits: point-antisymmetry G(-u,-v) = -G(u,v)  (already used)
//           x-mirror         G_{nd-d}(u,v) = G_d(u,-v)
// Per pair (d, nd-d): out_d = P + Q, out_{nd-d} = P - Q, where
//   P = sum over sym stream  of A*sval,  A = (G_d(u,v)+G_d(u,-v))/2
//   Q = sum over asym stream of B*dval,  B = (G_d(u,v)-G_d(u,-v))/2
// sym positions (63): (0,v) v=1..7 [sval=Delta], (u,0) u=1..7 [sval=Delta],
//                     (u,v) u,v=1..7 [sval=S=Delta(u,v)+Delta(u,-v)]
// asym positions (56): (0,v) v=1..7 [dval=Delta], (u,v) u,v=1..7 [dval=D]
// k=0 slots: sym -> d=nd/2 (x-symmetric filter), asym -> d=0 (x-antisym).
__global__ __launch_bounds__(256) void pack_tables(
    const double* __restrict__ gtmp, float* __restrict__ tab) {
    int s = blockIdx.x;  // 0..2
    int nh = (s == 0) ? 2 : (s == 1) ? 4 : 8;
    int fbase = (s == 0) ? 0 : (s == 1) ? 4 : 12;
    int symoff = (s == 0) ? SYM0 : (s == 1) ? SYM1 : SYM2;
    int asymoff = (s == 0) ? ASYM0 : (s == 1) ? ASYM1 : ASYM2;
    int nsym = 63 * nh, nasym = 56 * nh;

    for (int t = threadIdx.x; t < nsym + nasym; t += 256) {
        bool issym = t < nsym;
        int tt = issym ? t : t - nsym;
        int j = tt / nh, k = tt % nh;
        int u, v;
        if (issym) {
            if (j < 7)       { u = 0;         v = j + 1; }
            else if (j < 14) { u = j - 6;     v = 0;     }
            else { int p = j - 14; u = p / 7 + 1; v = p % 7 + 1; }
        } else {
            if (j < 7)       { u = 0;         v = j + 1; }
            else { int p = j - 7; u = p / 7 + 1; v = p % 7 + 1; }
        }
        int d = (k == 0) ? (issym ? nh : 0) : k;
        const double* F = gtmp + (long)(fbase + d) * 225;
        double gp = F[(7 + u) * 15 + (7 + v)];
        double gm = F[(7 + u) * 15 + (7 - v)];
        double val = issym ? 0.5 * (gp + gm) : 0.5 * (gp - gm);
        tab[(issym ? symoff : asymoff) + j * nh + k] = (float)val;
    }
}

// ---------------- 5x5 separable Gaussian lowpass, reflect pad --------------
__global__ __launch_bounds__(256) void lp_kernel(
    const float* __restrict__ in, float* __restrict__ out, long ostride) {
    int n = blockIdx.z;
    int x = blockIdx.x * 32 + threadIdx.x;
    int y = blockIdx.y * 8 + threadIdx.y;
    const float* ip = in + (long)n * HWSZ;

    float acc = 0.f;
#pragma unroll
    for (int fy = 0; fy < 5; ++fy) {
        int yy = refl(y + fy - 2, HH);
        const float* rp = ip + yy * WW;
        float rs = 0.f;
#pragma unroll
        for (int fx = 0; fx < 5; ++fx) {
            int xx = refl(x + fx - 2, WW);
            rs = fmaf(LPW[fx], rp[xx], rs);
        }
        acc = fmaf(LPW[fy], rs, acc);
    }
    out[(long)n * ostride + y * WW + x] = acc;
}

// ---------------- directional 15x15 bank, reflect pad ----------------------
// band = A[n] - B[n] computed on the fly. NH = nd/2 accumulator pairs.
template <int NH>
__global__ __launch_bounds__(256) void dir_kernel(
    const float* __restrict__ A, long as,
    const float* __restrict__ B, long bs,
    const float* __restrict__ symt, const float* __restrict__ asymt,
    float* __restrict__ out, int c0) {
    __shared__ float sm[46][48];

    int n = blockIdx.z;
    int tx = threadIdx.x, ty = threadIdx.y;
    int bx = blockIdx.x * 32, by = blockIdx.y * 32;

    const float* Ab = A + (long)n * as;
    const float* Bb = B + (long)n * bs;

    int lid = ty * 32 + tx;
    for (int l = lid; l < 46 * 46; l += 256) {
        int ly = l / 46, lx = l % 46;
        int gy = refl(by + ly - 7, HH);
        int gx = refl(bx + lx - 7, WW);
        long gi = (long)gy * WW + gx;
        sm[ly][lx] = Ab[gi] - Bb[gi];
    }
    __syncthreads();

    float accP[NH][4], accQ[NH][4];
#pragma unroll
    for (int k = 0; k < NH; ++k)
#pragma unroll
        for (int r = 0; r < 4; ++r) { accP[k][r] = 0.f; accQ[k][r] = 0.f; }

    int xc = tx + 7;

    // H0: u=0, v=1..7 : dval = sval = Delta(0,v), feeds both streams
#pragma unroll
    for (int v = 1; v <= 7; ++v) {
        float dv[4];
#pragma unroll
        for (int r = 0; r < 4; ++r) {
            int yb = ty + 7 + 8 * r;
            dv[r] = sm[yb][xc + v] - sm[yb][xc - v];
        }
#pragma unroll
        for (int k = 0; k < NH; ++k) {
            float cs = symt[(v - 1) * NH + k];   // wave-uniform -> s_load
            float ca = asymt[(v - 1) * NH + k];
#pragma unroll
            for (int r = 0; r < 4; ++r) {
                accP[k][r] = fmaf(cs, dv[r], accP[k][r]);
                accQ[k][r] = fmaf(ca, dv[r], accQ[k][r]);
            }
        }
    }

    // Hc: v=0, u=1..7 : sym stream only
#pragma unroll
    for (int u = 1; u <= 7; ++u) {
        float dv[4];
#pragma unroll
        for (int r = 0; r < 4; ++r) {
            int yb = ty + 7 + 8 * r;
            dv[r] = sm[yb + u][xc] - sm[yb - u][xc];
        }
#pragma unroll
        for (int k = 0; k < NH; ++k) {
            float cs = symt[(6 + u) * NH + k];
#pragma unroll
            for (int r = 0; r < 4; ++r)
                accP[k][r] = fmaf(cs, dv[r], accP[k][r]);
        }
    }

    // Hp: u=1..7, v=1..7 : S -> sym, D -> asym
#pragma unroll
    for (int u = 1; u <= 7; ++u) {
#pragma unroll
        for (int v = 1; v <= 7; ++v) {
            float S4[4], D4[4];
#pragma unroll
            for (int r = 0; r < 4; ++r) {
                int yb = ty + 7 + 8 * r;
                float a = sm[yb + u][xc + v];
                float b = sm[yb + u][xc - v];
                float c = sm[yb - u][xc + v];
                float d = sm[yb - u][xc - v];
                float t1 = a - d, t2 = b - c;
                S4[r] = t1 + t2;
                D4[r] = t1 - t2;
            }
            int jp = (u - 1) * 7 + (v - 1);
#pragma unroll
            for (int k = 0; k < NH; ++k) {
                float cs = symt[(14 + jp) * NH + k];
                float ca = asymt[(7 + jp) * NH + k];
#pragma unroll
                for (int r = 0; r < 4; ++r) {
                    accP[k][r] = fmaf(cs, S4[r], accP[k][r]);
                    accQ[k][r] = fmaf(ca, D4[r], accQ[k][r]);
                }
            }
        }
    }

    // outputs: d=0 -> Q[0]; d=NH -> P[0]; pair k: d=k -> P+Q, d=2NH-k -> P-Q
    long ob = ((long)n * 29 + c0) * HWSZ;
#pragma unroll
    for (int r = 0; r < 4; ++r) {
        long idx = ob + (long)(by + ty + r * 8) * WW + bx + tx;
        out[idx] = accQ[0][r];
        out[idx + (long)NH * HWSZ] = accP[0][r];
#pragma unroll
        for (int k = 1; k < NH; ++k) {
            out[idx + (long)k * HWSZ] = accP[k][r] + accQ[k][r];
            out[idx + (long)(2 * NH - k) * HWSZ] = accP[k][r] - accQ[k][r];
        }
    }
}

extern "C" void kernel_launch(void* const* d_in, const int* in_sizes, int n_in,
                              void* d_out, int out_size, void* d_ws, size_t ws_size,
                              hipStream_t stream) {
    const float* x = (const float*)d_in[0];
    float* out = (float*)d_out;
    float* ws = (float*)d_ws;

    float* tab = ws;                        // 1666 floats of packed tables
    float* lp0 = ws + 2048;                 // 24 * HWSZ
    float* lp1 = lp0 + (long)NIMG * HWSZ;   // 24 * HWSZ
    // fp64 scratch for raw filters; overlaps lp0 (dead before lp0 is written,
    // stream-ordered). 6300 doubles = 12600 floats << NIMG*HWSZ.
    double* gtmp = (double*)lp0;

    gen_filters<<<28, 256, 0, stream>>>(gtmp);
    pack_tables<<<3, 256, 0, stream>>>(gtmp, tab);

    dim3 blk(32, 8);
    dim3 lpgrid(12, 48, NIMG);
    // lp0 = LP(x); lp1 = LP(lp0); lp2 = LP(lp1) -> out channel 28
    lp_kernel<<<lpgrid, blk, 0, stream>>>(x, lp0, HWSZ);
    lp_kernel<<<lpgrid, blk, 0, stream>>>(lp0, lp1, HWSZ);
    lp_kernel<<<lpgrid, blk, 0, stream>>>(lp1, out + 28l * HWSZ, 29l * HWSZ);

    dim3 dgrid(12, 12, NIMG);
    // band0 = x - lp0      -> channels 0..3
    dir_kernel<2><<<dgrid, blk, 0, stream>>>(x, HWSZ, lp0, HWSZ,
                                             tab + SYM0, tab + ASYM0, out, 0);
    // band1 = lp0 - lp1    -> channels 4..11
    dir_kernel<4><<<dgrid, blk, 0, stream>>>(lp0, HWSZ, lp1, HWSZ,
                                             tab + SYM1, tab + ASYM1, out, 4);
    // band2 = lp1 - lp2    -> channels 12..27  (lp2 lives at out ch 28)
    dir_kernel<8><<<dgrid, blk, 0, stream>>>(lp1, HWSZ, out + 28l * HWSZ, 29l * HWSZ,
                                             tab + SYM2, tab + ASYM2, out, 12);
}

// Round 3
// 638.400 us; speedup vs baseline: 1.5839x; 1.5839x over previous
//
#include <hip/hip_runtime.h>

#define HH 384
#define WW 384
#define HWSZ (HH * WW)
#define NIMG 24

// packed coefficient table offsets (floats)
#define SYM0 0
#define ASYM0 126
#define SYM1 238
#define ASYM1 490
#define SYM2 714
#define ASYM2 1218

__device__ __forceinline__ int refl(int i, int n) {
    if (i < 0) i = -i;
    if (i >= n) i = 2 * n - 2 - i;
    return i;
}

// 5-tap Gaussian (sigma=1, normalized), double-precision constants cast to float
__device__ const float LPW[5] = {
    0.054488684549642945f, 0.24420134200323332f, 0.40261994689424746f,
    0.24420134200323332f, 0.054488684549642945f
};

// ---------------- filter generation (on device, fp64, matches numpy) -------
// Writes NORMALIZED fp64 filters to gtmp[28][225].
__global__ __launch_bounds__(256) void gen_filters(double* __restrict__ gtmp) {
    int f = blockIdx.x;  // 0..27
    int s, d, nd;
    if (f < 4)       { s = 0; nd = 4;  d = f;      }
    else if (f < 12) { s = 1; nd = 8;  d = f - 4;  }
    else             { s = 2; nd = 16; d = f - 12; }

    double angle = M_PI * (double)d / (double)nd;
    double scale = (double)(s + 1);
    double sx = 2.0 * scale, sy = 0.5 * scale;

    int tid = threadIdx.x;
    double val = 0.0;
    if (tid < 225) {
        int row = tid / 15, col = tid % 15;
        double X = (double)(col - 7);
        double Y = (double)(row - 7);
        double ca = cos(angle), sa = sin(angle);
        double Xr = X * ca - Y * sa;
        double Yr = X * sa + Y * ca;
        val = exp(-0.5 * (Xr * Xr / (sx * sx) + Yr * Yr / (sy * sy))) * Xr / (sx * sx);
    }

    __shared__ double red[256];
    red[tid] = val;
    __syncthreads();
    for (int st = 128; st > 0; st >>= 1) {
        if (tid < st) red[tid] += red[tid + st];
        __syncthreads();
    }
    double mean = red[0] / 225.0;
    __syncthreads();

    double dv = (tid < 225) ? (val - mean) : 0.0;
    red[tid] = dv * dv;
    __syncthreads();
    for (int st = 128; st > 0; st >>= 1) {
        if (tid < st) red[tid] += red[tid + st];
        __syncthreads();
    }
    double nrm = sqrt(red[0]);
    double inv = (nrm > 1e-6) ? (1.0 / nrm) : 1.0;

    if (tid < 225) {
        gtmp[(long)f * 225 + tid] = (val - mean) * inv;
    }
}

// ---------------- pack mirror-pair coefficient tables (fp64 combine) -------
// point-antisymmetry G(-u,-v) = -G(u,v); x-mirror G_{nd-d}(u,v) = G_d(u,-v).
// Per pair (d, nd-d): out_d = P + Q, out_{nd-d} = P - Q.
// sym positions (63): (0,v) v=1..7, (u,0) u=1..7, (u,v) u,v=1..7
// asym positions (56): (0,v) v=1..7, (u,v) u,v=1..7
// k=0 slots: sym -> d=nd/2 (x-symmetric filter), asym -> d=0 (x-antisym).
__global__ __launch_bounds__(256) void pack_tables(
    const double* __restrict__ gtmp, float* __restrict__ tab) {
    int s = blockIdx.x;  // 0..2
    int nh = (s == 0) ? 2 : (s == 1) ? 4 : 8;
    int fbase = (s == 0) ? 0 : (s == 1) ? 4 : 12;
    int symoff = (s == 0) ? SYM0 : (s == 1) ? SYM1 : SYM2;
    int asymoff = (s == 0) ? ASYM0 : (s == 1) ? ASYM1 : ASYM2;
    int nsym = 63 * nh, nasym = 56 * nh;

    for (int t = threadIdx.x; t < nsym + nasym; t += 256) {
        bool issym = t < nsym;
        int tt = issym ? t : t - nsym;
        int j = tt / nh, k = tt % nh;
        int u, v;
        if (issym) {
            if (j < 7)       { u = 0;         v = j + 1; }
            else if (j < 14) { u = j - 6;     v = 0;     }
            else { int p = j - 14; u = p / 7 + 1; v = p % 7 + 1; }
        } else {
            if (j < 7)       { u = 0;         v = j + 1; }
            else { int p = j - 7; u = p / 7 + 1; v = p % 7 + 1; }
        }
        int d = (k == 0) ? (issym ? nh : 0) : k;
        const double* F = gtmp + (long)(fbase + d) * 225;
        double gp = F[(7 + u) * 15 + (7 + v)];
        double gm = F[(7 + u) * 15 + (7 - v)];
        double val = issym ? 0.5 * (gp + gm) : 0.5 * (gp - gm);
        tab[(issym ? symoff : asymoff) + j * nh + k] = (float)val;
    }
}

// ---------------- 5x5 separable Gaussian lowpass, reflect pad --------------
__global__ __launch_bounds__(256) void lp_kernel(
    const float* __restrict__ in, float* __restrict__ out, long ostride) {
    int n = blockIdx.z;
    int x = blockIdx.x * 32 + threadIdx.x;
    int y = blockIdx.y * 8 + threadIdx.y;
    const float* ip = in + (long)n * HWSZ;

    float acc = 0.f;
#pragma unroll
    for (int fy = 0; fy < 5; ++fy) {
        int yy = refl(y + fy - 2, HH);
        const float* rp = ip + yy * WW;
        float rs = 0.f;
#pragma unroll
        for (int fx = 0; fx < 5; ++fx) {
            int xx = refl(x + fx - 2, WW);
            rs = fmaf(LPW[fx], rp[xx], rs);
        }
        acc = fmaf(LPW[fy], rs, acc);
    }
    out[(long)n * ostride + y * WW + x] = acc;
}

// ---------------- directional 15x15 bank, reflect pad ----------------------
// band = A[n] - B[n] computed on the fly. NH = nd/2 pairs, R = rows/thread.
// u-loop deliberately NOT unrolled: keeps code small and VGPR pressure low
// (round-2 full unroll gave 188 VGPR -> 11% occupancy -> 39% VALUBusy).
template <int NH, int R>
__global__ __launch_bounds__(256, 4) void dir_kernel(
    const float* __restrict__ A, long as,
    const float* __restrict__ B, long bs,
    const float* __restrict__ symt, const float* __restrict__ asymt,
    float* __restrict__ out, int c0) {
    constexpr int TH = 8 * R;            // tile height
    __shared__ float sm[TH + 14][48];

    int n = blockIdx.z;
    int tx = threadIdx.x, ty = threadIdx.y;
    int bx = blockIdx.x * 32, by = blockIdx.y * TH;

    const float* Ab = A + (long)n * as;
    const float* Bb = B + (long)n * bs;

    int lid = ty * 32 + tx;
    for (int l = lid; l < (TH + 14) * 46; l += 256) {
        int ly = l / 46, lx = l % 46;
        int gy = refl(by + ly - 7, HH);
        int gx = refl(bx + lx - 7, WW);
        long gi = (long)gy * WW + gx;
        sm[ly][lx] = Ab[gi] - Bb[gi];
    }
    __syncthreads();

    float accP[NH][R], accQ[NH][R];
#pragma unroll
    for (int k = 0; k < NH; ++k)
#pragma unroll
        for (int r = 0; r < R; ++r) { accP[k][r] = 0.f; accQ[k][r] = 0.f; }

    int xc = tx + 7;

    // H0: u=0, v=1..7 : dval = sval = Delta(0,v), feeds both streams
#pragma unroll
    for (int v = 1; v <= 7; ++v) {
        float dv[R];
#pragma unroll
        for (int r = 0; r < R; ++r) {
            int yb = ty + 7 + 8 * r;
            dv[r] = sm[yb][xc + v] - sm[yb][xc - v];
        }
#pragma unroll
        for (int k = 0; k < NH; ++k) {
            float cs = symt[(v - 1) * NH + k];   // wave-uniform -> s_load
            float ca = asymt[(v - 1) * NH + k];
#pragma unroll
            for (int r = 0; r < R; ++r) {
                accP[k][r] = fmaf(cs, dv[r], accP[k][r]);
                accQ[k][r] = fmaf(ca, dv[r], accQ[k][r]);
            }
        }
    }

    // u = 1..7 (runtime loop): Hc (v=0, sym only) + Hp (v=1..7, S->sym, D->asym)
#pragma unroll 1
    for (int u = 1; u <= 7; ++u) {
        // Hc
        {
            float dvc[R];
#pragma unroll
            for (int r = 0; r < R; ++r) {
                int yb = ty + 7 + 8 * r;
                dvc[r] = sm[yb + u][xc] - sm[yb - u][xc];
            }
#pragma unroll
            for (int k = 0; k < NH; ++k) {
                float cs = symt[(6 + u) * NH + k];
#pragma unroll
                for (int r = 0; r < R; ++r)
                    accP[k][r] = fmaf(cs, dvc[r], accP[k][r]);
            }
        }
        // Hp
#pragma unroll
        for (int v = 1; v <= 7; ++v) {
            float S[R], D[R];
#pragma unroll
            for (int r = 0; r < R; ++r) {
                int yb = ty + 7 + 8 * r;
                float a = sm[yb + u][xc + v];
                float b = sm[yb + u][xc - v];
                float c = sm[yb - u][xc + v];
                float d = sm[yb - u][xc - v];
                float t1 = a - d, t2 = b - c;
                S[r] = t1 + t2;
                D[r] = t1 - t2;
            }
            int jp = (u - 1) * 7 + (v - 1);
#pragma unroll
            for (int k = 0; k < NH; ++k) {
                float cs = symt[(14 + jp) * NH + k];
                float ca = asymt[(7 + jp) * NH + k];
#pragma unroll
                for (int r = 0; r < R; ++r) {
                    accP[k][r] = fmaf(cs, S[r], accP[k][r]);
                    accQ[k][r] = fmaf(ca, D[r], accQ[k][r]);
                }
            }
        }
    }

    // outputs: d=0 -> Q[0]; d=NH -> P[0]; pair k: d=k -> P+Q, d=2NH-k -> P-Q
    long ob = ((long)n * 29 + c0) * HWSZ;
#pragma unroll
    for (int r = 0; r < R; ++r) {
        long idx = ob + (long)(by + ty + r * 8) * WW + bx + tx;
        out[idx] = accQ[0][r];
        out[idx + (long)NH * HWSZ] = accP[0][r];
#pragma unroll
        for (int k = 1; k < NH; ++k) {
            out[idx + (long)k * HWSZ] = accP[k][r] + accQ[k][r];
            out[idx + (long)(2 * NH - k) * HWSZ] = accP[k][r] - accQ[k][r];
        }
    }
}

extern "C" void kernel_launch(void* const* d_in, const int* in_sizes, int n_in,
                              void* d_out, int out_size, void* d_ws, size_t ws_size,
                              hipStream_t stream) {
    const float* x = (const float*)d_in[0];
    float* out = (float*)d_out;
    float* ws = (float*)d_ws;

    float* tab = ws;                        // 1666 floats of packed tables
    float* lp0 = ws + 2048;                 // 24 * HWSZ
    float* lp1 = lp0 + (long)NIMG * HWSZ;   // 24 * HWSZ
    // fp64 scratch for raw filters; overlaps lp0 (dead before lp0 is written,
    // stream-ordered). 6300 doubles = 12600 floats << NIMG*HWSZ.
    double* gtmp = (double*)lp0;

    gen_filters<<<28, 256, 0, stream>>>(gtmp);
    pack_tables<<<3, 256, 0, stream>>>(gtmp, tab);

    dim3 blk(32, 8);
    dim3 lpgrid(12, 48, NIMG);
    // lp0 = LP(x); lp1 = LP(lp0); lp2 = LP(lp1) -> out channel 28
    lp_kernel<<<lpgrid, blk, 0, stream>>>(x, lp0, HWSZ);
    lp_kernel<<<lpgrid, blk, 0, stream>>>(lp0, lp1, HWSZ);
    lp_kernel<<<lpgrid, blk, 0, stream>>>(lp1, out + 28l * HWSZ, 29l * HWSZ);

    // band0 = x - lp0      -> channels 0..3   (NH=2, R=4: 32x32 tiles)
    dir_kernel<2, 4><<<dim3(12, 12, NIMG), blk, 0, stream>>>(
        x, HWSZ, lp0, HWSZ, tab + SYM0, tab + ASYM0, out, 0);
    // band1 = lp0 - lp1    -> channels 4..11  (NH=4, R=4: 32x32 tiles)
    dir_kernel<4, 4><<<dim3(12, 12, NIMG), blk, 0, stream>>>(
        lp0, HWSZ, lp1, HWSZ, tab + SYM1, tab + ASYM1, out, 4);
    // band2 = lp1 - lp2    -> channels 12..27 (NH=8, R=2: 32x16 tiles,
    // acc regs 64->32 to restore occupancy)
    dir_kernel<8, 2><<<dim3(12, 24, NIMG), blk, 0, stream>>>(
        lp1, HWSZ, out + 28l * HWSZ, 29l * HWSZ, tab + SYM2, tab + ASYM2, out, 12);
}